// Round 5
// baseline (49.956 us; speedup 1.0000x reference)
//
#include <hip/hip_runtime.h>
#include <math.h>

// QuGCN chain-product kernel, round 5.
// chain = v_0 * (prod_i c_i) * v_{E-1}^dag,  v_i = U f_i/|f_i|.
// U unitary => c_i = f_i.f_{i+1}/(|f_i||f_{i+1}|)  (REAL, U-independent).
// Thread t: items {2t,2t+1}; own 2 edge rows gathered, 3rd row via shfl_down(1)
// (lane 63 loads directly). prod(c_i^2) as num/den in double + sign-flip count;
// one frexp+logf per thread. |c_i|<=1 => f32 reference chain underflows to 0;
// gate s=0 when sum(log|c|) < -85.
//
// R5: single fused kernel via hierarchical last-block-done arrival.
//  - R1 lesson: one arrival counter = 1024 serialized same-address atomics
//    (~30cy each ~ 13us). Two-level: 32 group counters (64B apart) + 1 global
//    => ~0.8us arrival tail.
//  - R3 lesson: cg grid.sync costs ~60us; this pattern has NO spinning.
//  - Counters zeroed by a 2KB hipMemsetAsync node (d_ws poisoned once, never
//    re-poisoned => kernel must not rely on leftover state).
//  - Cross-XCD visibility: release threadfence before arrival, acquire after,
//    agent-scope atomic loads of partials.

#define W_MUL 0.63245553203367586640f  // sqrt(2/5)
#define LN2   0.69314718055994530942
#define TPB   256
#define GRP   32          // blocks per arrival group
#define CSTR  16          // counter stride in ints (64 B)

struct C { float re, im; };
__device__ __forceinline__ C cmul(C a, C b) {
    return { a.re * b.re - a.im * b.im, a.re * b.im + a.im * b.re };
}
__device__ __forceinline__ C cadd(C a, C b) { return { a.re + b.re, a.im + b.im }; }

__device__ __forceinline__ void build_U(const float* __restrict__ w, C U[4][4]) {
    float h0 = w[0] * W_MUL * 0.5f, h1 = w[1] * W_MUL * 0.5f, h2 = w[2] * W_MUL * 0.5f;
    float c0 = cosf(h0), s0 = sinf(h0);
    float c1 = cosf(h1), s1 = sinf(h1);
    float c2 = cosf(h2), s2 = sinf(h2);
    C rx[2][2] = { { {c0, 0.f}, {0.f, -s0} }, { {0.f, -s0}, {c0, 0.f} } };
    C ry[2][2] = { { {c1, 0.f}, {-s1, 0.f} }, { {s1, 0.f}, {c1, 0.f} } };
    C rz[2][2] = { { {c2, -s2}, {0.f, 0.f} }, { {0.f, 0.f}, {c2, s2} } };
    C t[2][2], u[2][2];
    for (int i = 0; i < 2; i++)
        for (int j = 0; j < 2; j++) {
            C a = {0.f, 0.f};
            for (int k = 0; k < 2; k++) a = cadd(a, cmul(ry[i][k], rx[k][j]));
            t[i][j] = a;
        }
    for (int i = 0; i < 2; i++)
        for (int j = 0; j < 2; j++) {
            C a = {0.f, 0.f};
            for (int k = 0; k < 2; k++) a = cadd(a, cmul(rz[i][k], t[k][j]));
            u[i][j] = a;
        }
    for (int a = 0; a < 2; a++)
        for (int b = 0; b < 2; b++)
            for (int c = 0; c < 2; c++)
                for (int d = 0; d < 2; d++)
                    U[2 * a + c][2 * b + d] = cmul(u[a][b], u[c][d]);
}

__device__ __forceinline__ void edge_v2(float2 fa, float2 fb, const C U[4][4], C v[4]) {
    float f[4] = { fa.x, fa.y, fb.x, fb.y };
    float n2 = f[0] * f[0] + f[1] * f[1] + f[2] * f[2] + f[3] * f[3];
    float inv = rsqrtf(n2);
    #pragma unroll
    for (int k = 0; k < 4; k++) {
        float re = 0.f, im = 0.f;
        #pragma unroll
        for (int j = 0; j < 4; j++) {
            re += U[k][j].re * f[j];
            im += U[k][j].im * f[j];
        }
        v[k] = { re * inv, im * inv };
    }
}

__global__ void __launch_bounds__(TPB)
k_all(const int* __restrict__ edges, const float2* __restrict__ nf,
      const float* __restrict__ weight, const float* __restrict__ lin_w,
      const float* __restrict__ lin_b, int nitems, int E,
      int nblocks, int ngroups,
      int* __restrict__ ctr, double* __restrict__ pL, int* __restrict__ pC,
      float* __restrict__ out) {
    // ---------------- phase 1: per-thread items {2t, 2t+1} ----------------
    int t = blockIdx.x * TPB + threadIdx.x;
    int i0 = 2 * t;
    int lane = threadIdx.x & 63;
    int Em1 = E - 1;

    double lsum = 0.0;
    int neg = 0;

    if (i0 <= Em1 - 1) {                  // rows i0, i0+1 exist
        int4 er = *(const int4*)(edges + 4 * t);   // rows i0, i0+1 (16B aligned)
        float2 fa0 = nf[er.x], fb0 = nf[er.y];
        float2 fa1 = nf[er.z], fb1 = nf[er.w];
        float n0 = fa0.x * fa0.x + fa0.y * fa0.y + fb0.x * fb0.x + fb0.y * fb0.y;
        float n1 = fa1.x * fa1.x + fa1.y * fa1.y + fb1.x * fb1.x + fb1.y * fb1.y;

        // neighbor row i0+2 from lane+1; lane 63 loads directly
        float2 fa2, fb2;
        float n2v;
        fa2.x = __shfl_down(fa0.x, 1, 64);
        fa2.y = __shfl_down(fa0.y, 1, 64);
        fb2.x = __shfl_down(fb0.x, 1, 64);
        fb2.y = __shfl_down(fb0.y, 1, 64);
        n2v   = __shfl_down(n0, 1, 64);
        if (lane == 63) {
            int r2 = (i0 + 2 <= Em1) ? (i0 + 2) : Em1;
            int2 e2 = *(const int2*)(edges + 2 * r2);
            fa2 = nf[e2.x];
            fb2 = nf[e2.y];
            n2v = fa2.x * fa2.x + fa2.y * fa2.y + fb2.x * fb2.x + fb2.y * fb2.y;
        }

        double num = 1.0, den = 1.0;
        if (i0 < nitems) {
            float d0 = fa0.x * fa1.x + fa0.y * fa1.y + fb0.x * fb1.x + fb0.y * fb1.y;
            num *= (double)(d0 * d0);
            den *= (double)(n0 * n1);
            neg += (d0 < 0.f) ? 1 : 0;
        }
        if (i0 + 1 < nitems) {
            float d1 = fa1.x * fa2.x + fa1.y * fa2.y + fb1.x * fb2.x + fb1.y * fb2.y;
            num *= (double)(d1 * d1);
            den *= (double)(n1 * n2v);
            neg += (d1 < 0.f) ? 1 : 0;
        }
        double Rt = num / den;            // prod c_i^2 in (0,1]
        int ex;
        double mf = frexp(Rt, &ex);
        lsum = 0.5 * ((double)ex * LN2 + (double)logf((float)mf)); // 0 -> -inf
    }

    for (int off = 32; off; off >>= 1) {
        lsum += __shfl_down(lsum, off, 64);
        neg  += __shfl_down(neg, off, 64);
    }
    __shared__ double sl[TPB / 64];
    __shared__ int    sn[TPB / 64];
    __shared__ int    amLast;
    int wid = threadIdx.x >> 6;
    if (lane == 0) { sl[wid] = lsum; sn[wid] = neg; }
    __syncthreads();

    // ---------------- arrival: hierarchical, no spinning ----------------
    if (threadIdx.x == 0) {
        double L = lsum; int N = neg;
        for (int w = 1; w < TPB / 64; w++) { L += sl[w]; N += sn[w]; }
        __hip_atomic_store(&pL[blockIdx.x], L, __ATOMIC_RELAXED, __HIP_MEMORY_SCOPE_AGENT);
        __hip_atomic_store(&pC[blockIdx.x], N, __ATOMIC_RELAXED, __HIP_MEMORY_SCOPE_AGENT);
        __threadfence();                          // release partials
        amLast = 0;
        int g = blockIdx.x / GRP;
        int gsize = min(GRP, nblocks - g * GRP);
        int old = __hip_atomic_fetch_add(&ctr[g * CSTR], 1,
                                         __ATOMIC_ACQ_REL, __HIP_MEMORY_SCOPE_AGENT);
        if (old == gsize - 1) {                   // last in group
            int old2 = __hip_atomic_fetch_add(&ctr[ngroups * CSTR], 1,
                                              __ATOMIC_ACQ_REL, __HIP_MEMORY_SCOPE_AGENT);
            if (old2 == ngroups - 1) amLast = 1;  // last overall
        }
    }
    __syncthreads();
    if (!amLast) return;

    // ---------------- phase 2: last block reduces + finalizes ----------------
    __threadfence();                              // acquire partials
    double L = 0.0; int N = 0;
    for (int i = threadIdx.x; i < nblocks; i += TPB) {
        L += __hip_atomic_load(&pL[i], __ATOMIC_RELAXED, __HIP_MEMORY_SCOPE_AGENT);
        N += __hip_atomic_load(&pC[i], __ATOMIC_RELAXED, __HIP_MEMORY_SCOPE_AGENT);
    }
    for (int off = 32; off; off >>= 1) {
        L += __shfl_down(L, off, 64);
        N += __shfl_down(N, off, 64);
    }
    __shared__ double sl2[TPB / 64];
    __shared__ int    sn2[TPB / 64];
    if (lane == 0) { sl2[wid] = L; sn2[wid] = N; }
    __syncthreads();
    if (threadIdx.x != 0) return;
    for (int w = 1; w < TPB / 64; w++) { L += sl2[w]; N += sn2[w]; }

    C U[4][4];
    build_U(weight, U);
    C v0[4], vl[4];
    edge_v2(nf[edges[0]], nf[edges[1]], U, v0);
    edge_v2(nf[edges[2 * Em1]], nf[edges[2 * Em1 + 1]], U, vl);

    float s_re;
    if (!(L > -85.0)) s_re = 0.f;                 // f32 chain underflowed
    else              s_re = (float)((N & 1) ? -exp(L) : exp(L));

    float x[16];
    for (int a = 0; a < 4; a++)
        for (int d = 0; d < 4; d++)
            x[4 * a + d] = s_re * (v0[a].re * vl[d].re + v0[a].im * vl[d].im);

    float l0 = lin_b[0], l1 = lin_b[1];
    for (int k = 0; k < 16; k++) {
        l0 += x[k] * lin_w[k];
        l1 += x[k] * lin_w[16 + k];
    }
    float mx = fmaxf(l0, l1);
    float e0 = expf(l0 - mx), e1 = expf(l1 - mx);
    float inv = 1.f / (e0 + e1);
    out[0] = e0 * inv;
    out[1] = e1 * inv;
}

extern "C" void kernel_launch(void* const* d_in, const int* in_sizes, int n_in,
                              void* d_out, int out_size, void* d_ws, size_t ws_size,
                              hipStream_t stream) {
    const int*    edges  = (const int*)d_in[0];     // [E,2] int32
    const float2* nf     = (const float2*)d_in[1];  // [N,2]
    const float*  weight = (const float*)d_in[2];   // [5]
    const float*  lin_w  = (const float*)d_in[3];   // [2,16]
    const float*  lin_b  = (const float*)d_in[4];   // [2]
    float* out = (float*)d_out;

    int E = in_sizes[0] / 2;
    int nitems = E - 1;

    int per_block = TPB * 2;
    int blocks = (nitems + per_block - 1) / per_block;  // 1024 for E=524288
    int ngroups = (blocks + GRP - 1) / GRP;             // 32

    int*    ctr = (int*)d_ws;                           // (ngroups+1)*CSTR ints
    double* pL  = (double*)((char*)d_ws + 4096);
    int*    pC  = (int*)(pL + blocks);

    // zero arrival counters (d_ws is poisoned once before timing, never re-poisoned)
    hipMemsetAsync(ctr, 0, (size_t)(ngroups + 1) * CSTR * sizeof(int), stream);

    k_all<<<blocks, TPB, 0, stream>>>(edges, nf, weight, lin_w, lin_b,
                                      nitems, E, blocks, ngroups,
                                      ctr, pL, pC, out);
}

// Round 6
// 21.147 us; speedup vs baseline: 2.3623x; 2.3623x over previous
//
#include <hip/hip_runtime.h>
#include <math.h>

// QuGCN chain-product kernel, round 6.
// chain = v_0 * (prod_i c_i) * v_{E-1}^dag,  v_i = U f_i/|f_i|.
// U unitary => c_i = f_i.f_{i+1}/(|f_i||f_{i+1}|)  (REAL, U-independent).
// Thread t: items {2t,2t+1}; own 2 edge rows gathered, 3rd row via shfl_down(1)
// (lane 63 loads directly). prod(c_i^2) as num/den in double + sign-flip count;
// one frexp+logf per thread. |c_i|<=1 => f32 reference chain underflows to 0;
// gate s=0 when sum(log|c|) < -85.
//
// R6: single kernel, cache-maintenance-free arrival.
//  - R5 lesson: per-block __threadfence / ACQ_REL agent atomics on gfx950 cost
//    an L2 flush/inv at the fabric (L2s are per-XCD, non-coherent): 1024 of
//    them serialized = +30us. AVOID device-scope fences per block.
//  - Partials transported BY relaxed agent atomicAdd (fabric-homed, no cache
//    maintenance), spread over 32 slot lines (64B apart, blockIdx&31).
//  - data-add -> arrival-add ordering via raw s_waitcnt vmcnt(0) (atomic acks
//    come from the coherence point => vmcnt(0) means performed).
//  - slot-last (relaxed fetch_add == expected-1) bumps one global counter;
//    winner (== nres-1) pays the ONLY __threadfence, reduces 32 slots,
//    finalizes serially in thread 0. No 2nd __syncthreads, no broadcast.
//  - R1 lesson (same-address atomic ~12-30ns serialized) respected: max 32
//    adds per line, lines parallel.
//  - slots+counters zeroed via 8KB hipMemsetAsync node each call.

#define W_MUL 0.63245553203367586640f  // sqrt(2/5)
#define LN2   0.69314718055994530942
#define TPB   256
#define NSLOT 32
#define DSTR  8     // double stride per slot line (64 B)
#define ISTR  16    // int stride per slot line (64 B)

struct C { float re, im; };
__device__ __forceinline__ C cmul(C a, C b) {
    return { a.re * b.re - a.im * b.im, a.re * b.im + a.im * b.re };
}
__device__ __forceinline__ C cadd(C a, C b) { return { a.re + b.re, a.im + b.im }; }

__device__ __forceinline__ void build_U(const float* __restrict__ w, C U[4][4]) {
    float h0 = w[0] * W_MUL * 0.5f, h1 = w[1] * W_MUL * 0.5f, h2 = w[2] * W_MUL * 0.5f;
    float c0 = cosf(h0), s0 = sinf(h0);
    float c1 = cosf(h1), s1 = sinf(h1);
    float c2 = cosf(h2), s2 = sinf(h2);
    C rx[2][2] = { { {c0, 0.f}, {0.f, -s0} }, { {0.f, -s0}, {c0, 0.f} } };
    C ry[2][2] = { { {c1, 0.f}, {-s1, 0.f} }, { {s1, 0.f}, {c1, 0.f} } };
    C rz[2][2] = { { {c2, -s2}, {0.f, 0.f} }, { {0.f, 0.f}, {c2, s2} } };
    C t[2][2], u[2][2];
    for (int i = 0; i < 2; i++)
        for (int j = 0; j < 2; j++) {
            C a = {0.f, 0.f};
            for (int k = 0; k < 2; k++) a = cadd(a, cmul(ry[i][k], rx[k][j]));
            t[i][j] = a;
        }
    for (int i = 0; i < 2; i++)
        for (int j = 0; j < 2; j++) {
            C a = {0.f, 0.f};
            for (int k = 0; k < 2; k++) a = cadd(a, cmul(rz[i][k], t[k][j]));
            u[i][j] = a;
        }
    for (int a = 0; a < 2; a++)
        for (int b = 0; b < 2; b++)
            for (int c = 0; c < 2; c++)
                for (int d = 0; d < 2; d++)
                    U[2 * a + c][2 * b + d] = cmul(u[a][b], u[c][d]);
}

__device__ __forceinline__ void edge_v2(float2 fa, float2 fb, const C U[4][4], C v[4]) {
    float f[4] = { fa.x, fa.y, fb.x, fb.y };
    float n2 = f[0] * f[0] + f[1] * f[1] + f[2] * f[2] + f[3] * f[3];
    float inv = rsqrtf(n2);
    #pragma unroll
    for (int k = 0; k < 4; k++) {
        float re = 0.f, im = 0.f;
        #pragma unroll
        for (int j = 0; j < 4; j++) {
            re += U[k][j].re * f[j];
            im += U[k][j].im * f[j];
        }
        v[k] = { re * inv, im * inv };
    }
}

__global__ void __launch_bounds__(TPB)
k_all(const int* __restrict__ edges, const float2* __restrict__ nf,
      const float* __restrict__ weight, const float* __restrict__ lin_w,
      const float* __restrict__ lin_b, int nitems, int E, int nblocks,
      double* __restrict__ pL, int* __restrict__ pC,
      int* __restrict__ ctr, int* __restrict__ gctr,
      float* __restrict__ out) {
    // ---------------- phase 1: per-thread items {2t, 2t+1} ----------------
    int t = blockIdx.x * TPB + threadIdx.x;
    int i0 = 2 * t;
    int lane = threadIdx.x & 63;
    int Em1 = E - 1;

    double lsum = 0.0;
    int neg = 0;

    if (i0 <= Em1 - 1) {                  // rows i0, i0+1 exist
        int4 er = *(const int4*)(edges + 4 * t);   // rows i0, i0+1 (16B aligned)
        float2 fa0 = nf[er.x], fb0 = nf[er.y];
        float2 fa1 = nf[er.z], fb1 = nf[er.w];
        float n0 = fa0.x * fa0.x + fa0.y * fa0.y + fb0.x * fb0.x + fb0.y * fb0.y;
        float n1 = fa1.x * fa1.x + fa1.y * fa1.y + fb1.x * fb1.x + fb1.y * fb1.y;

        // neighbor row i0+2 from lane+1; lane 63 loads directly
        float2 fa2, fb2;
        float n2v;
        fa2.x = __shfl_down(fa0.x, 1, 64);
        fa2.y = __shfl_down(fa0.y, 1, 64);
        fb2.x = __shfl_down(fb0.x, 1, 64);
        fb2.y = __shfl_down(fb0.y, 1, 64);
        n2v   = __shfl_down(n0, 1, 64);
        if (lane == 63) {
            int r2 = (i0 + 2 <= Em1) ? (i0 + 2) : Em1;
            int2 e2 = *(const int2*)(edges + 2 * r2);
            fa2 = nf[e2.x];
            fb2 = nf[e2.y];
            n2v = fa2.x * fa2.x + fa2.y * fa2.y + fb2.x * fb2.x + fb2.y * fb2.y;
        }

        double num = 1.0, den = 1.0;
        if (i0 < nitems) {
            float d0 = fa0.x * fa1.x + fa0.y * fa1.y + fb0.x * fb1.x + fb0.y * fb1.y;
            num *= (double)(d0 * d0);
            den *= (double)(n0 * n1);
            neg += (d0 < 0.f) ? 1 : 0;
        }
        if (i0 + 1 < nitems) {
            float d1 = fa1.x * fa2.x + fa1.y * fa2.y + fb1.x * fb2.x + fb1.y * fb2.y;
            num *= (double)(d1 * d1);
            den *= (double)(n1 * n2v);
            neg += (d1 < 0.f) ? 1 : 0;
        }
        double Rt = num / den;            // prod c_i^2 in (0,1]
        int ex;
        double mf = frexp(Rt, &ex);
        lsum = 0.5 * ((double)ex * LN2 + (double)logf((float)mf)); // 0 -> -inf
    }

    for (int off = 32; off; off >>= 1) {
        lsum += __shfl_down(lsum, off, 64);
        neg  += __shfl_down(neg, off, 64);
    }
    __shared__ double sl[TPB / 64];
    __shared__ int    sn[TPB / 64];
    int wid = threadIdx.x >> 6;
    if (lane == 0) { sl[wid] = lsum; sn[wid] = neg; }
    __syncthreads();
    if (threadIdx.x != 0) return;         // only thread 0 runs the protocol

    double L = lsum; int N = neg;
    for (int w = 1; w < TPB / 64; w++) { L += sl[w]; N += sn[w]; }

    // ------------- arrival: relaxed fabric atomics, no fences -------------
    int s = blockIdx.x & (NSLOT - 1);
    __hip_atomic_fetch_add(&pL[s * DSTR], L, __ATOMIC_RELAXED, __HIP_MEMORY_SCOPE_AGENT);
    __hip_atomic_fetch_add(&pC[s * ISTR], N, __ATOMIC_RELAXED, __HIP_MEMORY_SCOPE_AGENT);
    // atomic acks come from the coherence point: vmcnt(0) => adds performed
    asm volatile("s_waitcnt vmcnt(0)" ::: "memory");

    int expected = (nblocks - s + NSLOT - 1) >> 5;    // blocks with this residue
    int old = __hip_atomic_fetch_add(&ctr[s * ISTR], 1,
                                     __ATOMIC_RELAXED, __HIP_MEMORY_SCOPE_AGENT);
    if (old != expected - 1) return;                  // not slot-last

    int nres = (nblocks < NSLOT) ? nblocks : NSLOT;
    int old2 = __hip_atomic_fetch_add(gctr, 1,
                                      __ATOMIC_RELAXED, __HIP_MEMORY_SCOPE_AGENT);
    if (old2 != nres - 1) return;                     // not winner

    // ---------------- winner: the ONLY device-scope fence ----------------
    __threadfence();
    double Lt = 0.0; int Nt = 0;
    #pragma unroll
    for (int i = 0; i < NSLOT; i++) {
        if (i >= nres) break;
        Lt += __hip_atomic_load(&pL[i * DSTR], __ATOMIC_RELAXED, __HIP_MEMORY_SCOPE_AGENT);
        Nt += __hip_atomic_load(&pC[i * ISTR], __ATOMIC_RELAXED, __HIP_MEMORY_SCOPE_AGENT);
    }

    C U[4][4];
    build_U(weight, U);
    C v0[4], vl[4];
    edge_v2(nf[edges[0]], nf[edges[1]], U, v0);
    edge_v2(nf[edges[2 * Em1]], nf[edges[2 * Em1 + 1]], U, vl);

    float s_re;
    if (!(Lt > -85.0)) s_re = 0.f;                // f32 chain underflowed
    else               s_re = (float)((Nt & 1) ? -exp(Lt) : exp(Lt));

    float x[16];
    for (int a = 0; a < 4; a++)
        for (int d = 0; d < 4; d++)
            x[4 * a + d] = s_re * (v0[a].re * vl[d].re + v0[a].im * vl[d].im);

    float l0 = lin_b[0], l1 = lin_b[1];
    for (int k = 0; k < 16; k++) {
        l0 += x[k] * lin_w[k];
        l1 += x[k] * lin_w[16 + k];
    }
    float mx = fmaxf(l0, l1);
    float e0 = expf(l0 - mx), e1 = expf(l1 - mx);
    float inv = 1.f / (e0 + e1);
    out[0] = e0 * inv;
    out[1] = e1 * inv;
}

extern "C" void kernel_launch(void* const* d_in, const int* in_sizes, int n_in,
                              void* d_out, int out_size, void* d_ws, size_t ws_size,
                              hipStream_t stream) {
    const int*    edges  = (const int*)d_in[0];     // [E,2] int32
    const float2* nf     = (const float2*)d_in[1];  // [N,2]
    const float*  weight = (const float*)d_in[2];   // [5]
    const float*  lin_w  = (const float*)d_in[3];   // [2,16]
    const float*  lin_b  = (const float*)d_in[4];   // [2]
    float* out = (float*)d_out;

    int E = in_sizes[0] / 2;
    int nitems = E - 1;

    int per_block = TPB * 2;
    int blocks = (nitems + per_block - 1) / per_block;  // 1024 for E=524288

    // d_ws layout: [0,2KB) pL slots; [2KB,4KB) pC slots; [4KB,6KB) ctr;
    //              [6KB,6KB+64) gctr. All zeroed each call.
    double* pL   = (double*)d_ws;
    int*    pC   = (int*)((char*)d_ws + 2048);
    int*    ctr  = (int*)((char*)d_ws + 4096);
    int*    gctr = (int*)((char*)d_ws + 6144);

    hipMemsetAsync(d_ws, 0, 8192, stream);

    k_all<<<blocks, TPB, 0, stream>>>(edges, nf, weight, lin_w, lin_b,
                                      nitems, E, blocks,
                                      pL, pC, ctr, gctr, out);
}

// Round 7
// 16.801 us; speedup vs baseline: 2.9733x; 1.2587x over previous
//
#include <hip/hip_runtime.h>
#include <math.h>

// QuGCN chain-product kernel, round 7.
// chain = v_0 * (prod_i c_i) * v_{E-1}^dag,  v_i = U f_i/|f_i|.
// U unitary => c_i = f_i.f_{i+1}/(|f_i||f_{i+1}|)  (REAL, U-independent).
// |c_i|<=1 => the f32 reference chain underflows to exactly 0; gate s=0 when
// sum(log|c|) < -85 (below f32 normal range; ref is 0 there).
//
// Structure: R4's two plain kernels (proven fastest). R3/R5/R6 lessons:
// every cross-block completion scheme on gfx950 loses to a second dispatch
// (coop grid.sync ~60us; per-block acq-rel fences ~30us; relaxed-atomic
// arrival ~+5us tail). Dispatch overhead is the floor; minimize kernel exec.
//
// R7 changes vs R4 (15.8us):
//  - k_part: 1 item/thread (2048 blocks, 8192 waves -> 2x TLP), dependent
//    chain = one int2 edge load -> 2 gathers. Row t+1 via shfl_down(1);
//    lane 63 loads it directly.
//  - per-item log in f32 (logf(d^2/(n0*n1))), accumulated in f64. No f64
//    div/frexp. d^2 underflow -> -inf -> gate -> s=0 (matches reference).
//  - block partial packed as double2 {L, (double)N} -> k_fin halves loads.

#define W_MUL 0.63245553203367586640f  // sqrt(2/5)
#define TPB   256

struct C { float re, im; };
__device__ __forceinline__ C cmul(C a, C b) {
    return { a.re * b.re - a.im * b.im, a.re * b.im + a.im * b.re };
}
__device__ __forceinline__ C cadd(C a, C b) { return { a.re + b.re, a.im + b.im }; }

__device__ __forceinline__ void build_U(const float* __restrict__ w, C U[4][4]) {
    float h0 = w[0] * W_MUL * 0.5f, h1 = w[1] * W_MUL * 0.5f, h2 = w[2] * W_MUL * 0.5f;
    float c0 = cosf(h0), s0 = sinf(h0);
    float c1 = cosf(h1), s1 = sinf(h1);
    float c2 = cosf(h2), s2 = sinf(h2);
    C rx[2][2] = { { {c0, 0.f}, {0.f, -s0} }, { {0.f, -s0}, {c0, 0.f} } };
    C ry[2][2] = { { {c1, 0.f}, {-s1, 0.f} }, { {s1, 0.f}, {c1, 0.f} } };
    C rz[2][2] = { { {c2, -s2}, {0.f, 0.f} }, { {0.f, 0.f}, {c2, s2} } };
    C t[2][2], u[2][2];
    for (int i = 0; i < 2; i++)
        for (int j = 0; j < 2; j++) {
            C a = {0.f, 0.f};
            for (int k = 0; k < 2; k++) a = cadd(a, cmul(ry[i][k], rx[k][j]));
            t[i][j] = a;
        }
    for (int i = 0; i < 2; i++)
        for (int j = 0; j < 2; j++) {
            C a = {0.f, 0.f};
            for (int k = 0; k < 2; k++) a = cadd(a, cmul(rz[i][k], t[k][j]));
            u[i][j] = a;
        }
    for (int a = 0; a < 2; a++)
        for (int b = 0; b < 2; b++)
            for (int c = 0; c < 2; c++)
                for (int d = 0; d < 2; d++)
                    U[2 * a + c][2 * b + d] = cmul(u[a][b], u[c][d]);
}

__device__ __forceinline__ void edge_v2(float2 fa, float2 fb, const C U[4][4], C v[4]) {
    float f[4] = { fa.x, fa.y, fb.x, fb.y };
    float n2 = f[0] * f[0] + f[1] * f[1] + f[2] * f[2] + f[3] * f[3];
    float inv = rsqrtf(n2);
    #pragma unroll
    for (int k = 0; k < 4; k++) {
        float re = 0.f, im = 0.f;
        #pragma unroll
        for (int j = 0; j < 4; j++) {
            re += U[k][j].re * f[j];
            im += U[k][j].im * f[j];
        }
        v[k] = { re * inv, im * inv };
    }
}

// phase 1: thread t handles item t (rows t, t+1); block partial -> part[blockIdx]
__global__ void __launch_bounds__(TPB)
k_part(const int* __restrict__ edges, const float2* __restrict__ nf,
       int nitems, double2* __restrict__ part) {
    int t = blockIdx.x * TPB + threadIdx.x;
    int lane = threadIdx.x & 63;
    int Em1 = nitems;                 // last valid row index = E-1

    // own row t (valid for every launched thread: grid = ceil(E/TPB)*TPB,
    // clamp the (rare) overhang)
    int r = (t <= Em1) ? t : Em1;
    int2 e = *(const int2*)(edges + 2 * r);
    float2 fa0 = nf[e.x], fb0 = nf[e.y];
    float n0 = fa0.x * fa0.x + fa0.y * fa0.y + fb0.x * fb0.x + fb0.y * fb0.y;

    // row t+1 from lane+1; lane 63 loads directly
    float ax = __shfl_down(fa0.x, 1, 64);
    float ay = __shfl_down(fa0.y, 1, 64);
    float bx = __shfl_down(fb0.x, 1, 64);
    float by = __shfl_down(fb0.y, 1, 64);
    float n1 = __shfl_down(n0, 1, 64);
    if (lane == 63) {
        int r1 = (t + 1 <= Em1) ? (t + 1) : Em1;
        int2 e1 = *(const int2*)(edges + 2 * r1);
        float2 fa1 = nf[e1.x], fb1 = nf[e1.y];
        ax = fa1.x; ay = fa1.y; bx = fb1.x; by = fb1.y;
        n1 = ax * ax + ay * ay + bx * bx + by * by;
    }

    double lsum = 0.0;
    int neg = 0;
    if (t < nitems) {
        float d = fa0.x * ax + fa0.y * ay + fb0.x * bx + fb0.y * by;
        float ratio = (d * d) / (n0 * n1);        // c^2 in (0,1]; 0 on underflow
        lsum = 0.5 * (double)logf(ratio);          // logf(0) = -inf (gated later)
        neg = (d < 0.f) ? 1 : 0;
    }

    for (int off = 32; off; off >>= 1) {
        lsum += __shfl_down(lsum, off, 64);
        neg  += __shfl_down(neg, off, 64);
    }
    __shared__ double sl[TPB / 64];
    __shared__ int    sn[TPB / 64];
    int wid = threadIdx.x >> 6;
    if (lane == 0) { sl[wid] = lsum; sn[wid] = neg; }
    __syncthreads();
    if (threadIdx.x == 0) {
        double L = lsum; int N = neg;
        for (int w = 1; w < TPB / 64; w++) { L += sl[w]; N += sn[w]; }
        part[blockIdx.x] = { L, (double)N };
    }
}

// phase 2: reduce partials, finalize
__global__ void __launch_bounds__(TPB)
k_fin(const int* __restrict__ edges, const float2* __restrict__ nf,
      const float* __restrict__ weight, const float* __restrict__ lin_w,
      const float* __restrict__ lin_b, int E, int nparts,
      const double2* __restrict__ part, float* __restrict__ out) {
    int t = threadIdx.x;
    double L = 0.0, Nd = 0.0;
    for (int i = t; i < nparts; i += TPB) {
        double2 p = part[i];
        L += p.x; Nd += p.y;
    }
    for (int off = 32; off; off >>= 1) {
        L  += __shfl_down(L, off, 64);
        Nd += __shfl_down(Nd, off, 64);
    }
    __shared__ double sl2[TPB / 64];
    __shared__ double sn2[TPB / 64];
    int wid = t >> 6, lane = t & 63;
    if (lane == 0) { sl2[wid] = L; sn2[wid] = Nd; }
    __syncthreads();
    if (t != 0) return;
    for (int w = 1; w < TPB / 64; w++) { L += sl2[w]; Nd += sn2[w]; }
    long long N = (long long)Nd;                    // exact (integer < 2^53)

    C U[4][4];
    build_U(weight, U);
    C v0[4], vl[4];
    edge_v2(nf[edges[0]], nf[edges[1]], U, v0);
    edge_v2(nf[edges[2 * (E - 1)]], nf[edges[2 * (E - 1) + 1]], U, vl);

    float s_re;
    if (!(L > -85.0)) s_re = 0.f;                   // f32 chain underflowed
    else              s_re = (float)((N & 1) ? -exp(L) : exp(L));

    float x[16];
    for (int a = 0; a < 4; a++)
        for (int d = 0; d < 4; d++)
            x[4 * a + d] = s_re * (v0[a].re * vl[d].re + v0[a].im * vl[d].im);

    float l0 = lin_b[0], l1 = lin_b[1];
    for (int k = 0; k < 16; k++) {
        l0 += x[k] * lin_w[k];
        l1 += x[k] * lin_w[16 + k];
    }
    float mx = fmaxf(l0, l1);
    float e0 = expf(l0 - mx), e1 = expf(l1 - mx);
    float inv = 1.f / (e0 + e1);
    out[0] = e0 * inv;
    out[1] = e1 * inv;
}

extern "C" void kernel_launch(void* const* d_in, const int* in_sizes, int n_in,
                              void* d_out, int out_size, void* d_ws, size_t ws_size,
                              hipStream_t stream) {
    const int*    edges  = (const int*)d_in[0];     // [E,2] int32
    const float2* nf     = (const float2*)d_in[1];  // [N,2]
    const float*  weight = (const float*)d_in[2];   // [5]
    const float*  lin_w  = (const float*)d_in[3];   // [2,16]
    const float*  lin_b  = (const float*)d_in[4];   // [2]
    float* out = (float*)d_out;

    int E = in_sizes[0] / 2;
    int nitems = E - 1;

    int blocks = (E + TPB - 1) / TPB;               // 2048 for E=524288

    double2* part = (double2*)d_ws;                 // [blocks] double2

    k_part<<<blocks, TPB, 0, stream>>>(edges, nf, nitems, part);
    k_fin<<<1, TPB, 0, stream>>>(edges, nf, weight, lin_w, lin_b,
                                 E, blocks, part, out);
}